// Round 10
// baseline (433.467 us; speedup 1.0000x reference)
//
#include <hip/hip_runtime.h>
#include <hip/hip_bf16.h>
#include <math.h>

#define NN 20000
#define EE 640000
#define NB 157      // buckets of 128 dst nodes
#define BCAP 5120   // per-bucket capacity (mean 4076 + 16 sigma)
#define NBLK 160    // binning blocks per type
#define CHNK 4000   // edges per binning block

typedef float v2f __attribute__((ext_vector_type(2)));
typedef __attribute__((ext_vector_type(8))) short bf16x8;
typedef __attribute__((ext_vector_type(4))) float f32x4;

__device__ __forceinline__ void wave_fence() {
  __builtin_amdgcn_wave_barrier();
  asm volatile("s_waitcnt lgkmcnt(0)" ::: "memory");
  __builtin_amdgcn_wave_barrier();
}

__device__ __forceinline__ unsigned pack_bf2(float a, float b) {
  __hip_bfloat162 h2 = __float22bfloat162_rn(make_float2(a, b));
  return *(unsigned*)&h2;
}
__device__ __forceinline__ float2 unpack_bf2(unsigned v) {
  float2 r;
  unsigned lo = v << 16, hi = v & 0xffff0000u;
  r.x = __uint_as_float(lo);
  r.y = __uint_as_float(hi);
  return r;
}

// ---------------- CSR build pass 1: bin edges by dst>>7 (grid-strided, packed) ----------------
__global__ __launch_bounds__(256) void bin_k(const int* __restrict__ ea,
                                             const int* __restrict__ eb,
                                             int* __restrict__ gcnt,
                                             int* __restrict__ bbuf) {
  int t = blockIdx.y;
  const int* ei = t ? eb : ea;
  int tid = threadIdx.x;
  __shared__ int lh[NB], lbase[NB];
  if (tid < NB) lh[tid] = 0;
  __syncthreads();
  int e0 = blockIdx.x * CHNK;
  int e1 = min(e0 + CHNK, EE);
  int myb[16], myr[16], myv[16];
#pragma unroll
  for (int i = 0; i < 16; ++i) {
    int e = e0 + tid + i * 256;
    if (e < e1) {
      int s = ei[e], d = ei[EE + e];
      int b = d >> 7;
      myb[i] = b;
      myv[i] = (s << 7) | (d & 127);
      myr[i] = atomicAdd(&lh[b], 1);
    } else {
      myb[i] = -1;
    }
  }
  __syncthreads();
  if (tid < NB) {
    int c = lh[tid];
    lbase[tid] = c ? atomicAdd(&gcnt[t * NB + tid], c) : 0;
  }
  __syncthreads();
#pragma unroll
  for (int i = 0; i < 16; ++i) {
    int b = myb[i];
    if (b >= 0) {
      int pos = lbase[b] + myr[i];
      if (pos < BCAP) bbuf[((size_t)t * NB + b) * BCAP + pos] = myv[i];
    }
  }
}

// ---------------- CSR build pass 2a: parallel segmented scan of bucket counts ----------------
__global__ __launch_bounds__(512) void bscan_k(const int* __restrict__ gcnt,
                                               int* __restrict__ bstart) {
  __shared__ int buf[512];
  int tid = threadIdx.x;
  int t = tid >> 8, b = tid & 255;
  int val = (b < NB) ? gcnt[t * NB + b] : 0;
  buf[tid] = val;
  __syncthreads();
  for (int s = 1; s < 256; s <<= 1) {
    int x = ((tid & 255) >= s) ? buf[tid - s] : 0;
    __syncthreads();
    buf[tid] += x;
    __syncthreads();
  }
  if (b < NB) bstart[t * NB + b] = buf[tid] - val;
}

// ---------------- CSR build pass 2b: per-bucket local counting sort ----------------
__global__ __launch_bounds__(256) void build_k(const int* __restrict__ gcnt,
                                               const int* __restrict__ bstart,
                                               const int* __restrict__ bbuf,
                                               int* __restrict__ rowptr,
                                               int* __restrict__ csr) {
  int b = blockIdx.x, t = blockIdx.y;
  int cnt = gcnt[t * NB + b];
  int start = bstart[t * NB + b];
  int n0 = b << 7;
  int nlocal = min(128, NN - n0);
  int tid = threadIdx.x;
  __shared__ int arr[128], lcur[128];
  if (tid < 128) arr[tid] = 0;
  __syncthreads();
  const int* ebuf = bbuf + ((size_t)t * NB + b) * BCAP;
  for (int i = tid; i < cnt; i += 256) atomicAdd(&arr[ebuf[i] & 127], 1);
  __syncthreads();
  int deg = (tid < 128) ? arr[tid] : 0;
  for (int s = 1; s < 128; s <<= 1) {
    int x = (tid < 128 && tid >= s) ? arr[tid - s] : 0;
    __syncthreads();
    if (tid < 128) arr[tid] += x;
    __syncthreads();
  }
  if (tid < nlocal) {
    int incl = arr[tid];
    rowptr[t * (NN + 1) + n0 + tid + 1] = start + incl;
    lcur[tid] = start + incl - deg;
  }
  if (b == 0 && tid == 0) rowptr[t * (NN + 1)] = 0;
  __syncthreads();
  for (int i = tid; i < cnt; i += 256) {
    int v = ebuf[i];
    int pos = atomicAdd(&lcur[v & 127], 1);
    csr[(size_t)t * EE + pos] = v >> 7;
  }
}

// ---------------- pack x to bf16 words: Xp[n][128] ----------------
__global__ void packx_k(const float* __restrict__ x, unsigned* __restrict__ Xp) {
  int idx = blockIdx.x * 256 + threadIdx.x;
  if (idx >= NN * 128) return;
  float2 f = *(const float2*)&x[(size_t)idx * 2];
  Xp[idx] = pack_bf2(f.x, f.y);
}

// ---------------- fold W1 transposed + bf16-packed: BT1[t][col 128][kword 128] ----------------
// W1: [2][256 k][128 c]; word kw of col c = k-pair (2kw, 2kw+1).
__global__ void foldBT1_k(const float* __restrict__ W1, unsigned* __restrict__ BT1) {
  int idx = blockIdx.x * 256 + threadIdx.x;
  if (idx >= 32768) return;
  int t = idx >> 14, r = idx & 16383, c = r >> 7, kw = r & 127;
  float v0 = W1[(size_t)t * 32768 + (size_t)(2 * kw) * 128 + c];
  float v1 = W1[(size_t)t * 32768 + (size_t)(2 * kw + 1) * 128 + c];
  BT1[idx] = pack_bf2(v0, v1);
}

// ---------------- layer-1 GEMM via MFMA, both types: h1b[t] = bf16(Xp @ W1[t]) ----------------
// Same fragment conventions as gemm2_k (hardware-proven): A lane l elem j = A[l&15][(l>>4)*8+j];
// B lane l elem j = B[(l>>4)*8+j][l&15]; D lane l reg r = C[(l>>4)*4+r][l&15].
// Epilogue packs col-pairs via shfl_xor(1) (aggm MODE-1 pattern, proven R7).
__global__ __launch_bounds__(256) void gemm1_k(const unsigned* __restrict__ Xp,
                                               const unsigned* __restrict__ BT1,
                                               unsigned* __restrict__ h1b) {
  int tid = threadIdx.x, w = tid >> 6, l = tid & 63;
  int lr = l & 15, lg = l >> 4;
  int rowbase = blockIdx.x * 64 + w * 16;
  int arow = rowbase + lr;
  if (arow > NN - 1) arow = NN - 1;   // clamp: garbage-free load, store is guarded
  f32x4 acc[2][8];
#pragma unroll
  for (int t = 0; t < 2; ++t)
#pragma unroll
    for (int ct = 0; ct < 8; ++ct) acc[t][ct] = (f32x4){0.f, 0.f, 0.f, 0.f};
  const unsigned* ap = Xp + (size_t)arow * 128 + lg * 4;
#pragma unroll
  for (int kw = 0; kw < 128; kw += 16) {   // 8 k-steps of 32 k-elements
    uint4 av = *(const uint4*)(ap + kw);
    bf16x8 af = *(const bf16x8*)&av;
#pragma unroll
    for (int t = 0; t < 2; ++t) {
#pragma unroll
      for (int ct = 0; ct < 8; ++ct) {
        uint4 bv = *(const uint4*)(BT1 + (size_t)t * 16384 + (size_t)(ct * 16 + lr) * 128 + lg * 4 + kw);
        acc[t][ct] = __builtin_amdgcn_mfma_f32_16x16x32_bf16(af, *(const bf16x8*)&bv, acc[t][ct], 0, 0, 0);
      }
    }
  }
  bool wr = (l & 1) == 0;
#pragma unroll
  for (int t = 0; t < 2; ++t) {
#pragma unroll
    for (int ct = 0; ct < 8; ++ct) {
      int col = ct * 16 + lr;
#pragma unroll
      for (int r = 0; r < 4; ++r) {
        float v = acc[t][ct][r];
        float v2 = __shfl_xor(v, 1);
        int row = rowbase + lg * 4 + r;
        if (wr && row < NN)
          h1b[(size_t)t * NN * 64 + (size_t)row * 64 + (col >> 1)] = pack_bf2(v, v2);
      }
    }
  }
}

// ---------------- layer-1 attention scores from bf16-packed h1b ----------------
__global__ void scoreb_k(const unsigned* __restrict__ hb, const float* __restrict__ as_,
                         const float* __restrict__ ad_, float* __restrict__ ss,
                         float* __restrict__ sd) {
  int idx = blockIdx.x * 256 + threadIdx.x;
  if (idx >= 2 * NN * 8) return;
  int t = idx / (NN * 8), r = idx % (NN * 8), n = r / 8, hh = r % 8;
  const unsigned* hrow = hb + (size_t)t * NN * 64 + (size_t)n * 64 + hh * 8;
  const float* a1 = as_ + t * 128 + hh * 16;
  const float* a2 = ad_ + t * 128 + hh * 16;
  uint4 u0 = *(const uint4*)&hrow[0];
  uint4 u1 = *(const uint4*)&hrow[4];
  unsigned uu[8] = {u0.x, u0.y, u0.z, u0.w, u1.x, u1.y, u1.z, u1.w};
  float s1 = 0.f, s2 = 0.f;
#pragma unroll
  for (int q = 0; q < 8; ++q) {
    float2 f = unpack_bf2(uu[q]);
    s1 += f.x * a1[2 * q] + f.y * a1[2 * q + 1];
    s2 += f.x * a2[2 * q] + f.y * a2[2 * q + 1];
  }
  ss[idx] = s1; sd[idx] = s2;
}

__device__ __forceinline__ float lrelu(float v) { return v > 0.f ? v : 0.2f * v; }

// ---------------- layer-1 aggregation: wave per node, 8-deep pipelined bf16 gather ----------------
// Output now bf16-packed: o1p[t][n][64 words].
__global__ __launch_bounds__(256) void aggw1_k(const int* __restrict__ rowptr,
                                               const int* __restrict__ csr,
                                               const float* __restrict__ ssrc,
                                               const float* __restrict__ sdst,
                                               const unsigned* __restrict__ hb,
                                               unsigned* __restrict__ out) {
  int t = blockIdx.y;
  rowptr += t * (NN + 1); csr += (size_t)t * EE;
  ssrc += (size_t)t * NN * 8; sdst += (size_t)t * NN * 8;
  hb += (size_t)t * NN * 64; out += (size_t)t * NN * 64;
  int tid = threadIdx.x, w = tid >> 6, lane = tid & 63;
  int n = blockIdx.x * 4 + w;
  int row = rowptr[n], end = rowptr[n + 1];
  __shared__ __align__(16) int sidx[4][64];
  __shared__ __align__(16) float sexp[4][64][8];
  float4 sda = *(const float4*)&sdst[(size_t)n * 8];
  float4 sdb = *(const float4*)&sdst[(size_t)n * 8 + 4];
  float za_x = 0.f, za_y = 0.f, za_z = 0.f, za_w = 0.f;
  float zb_x = 0.f, zb_y = 0.f, zb_z = 0.f, zb_w = 0.f;
  int hme = lane >> 3;
  unsigned lane4 = lane << 2;
  const char* hbc = (const char*)hb;
  v2f acc = {0.f, 0.f};
  for (int base = row; base < end; base += 64) {
    int cnt = min(64, end - base);
    if (lane < cnt) {
      int s = csr[base + lane];
      sidx[w][lane] = s << 8;            // byte offset into hb (64 words/row)
      float4 pa = *(const float4*)&ssrc[(size_t)s * 8];
      float4 pb = *(const float4*)&ssrc[(size_t)s * 8 + 4];
      float4 ea, eb;
      ea.x = __expf(lrelu(pa.x + sda.x)); ea.y = __expf(lrelu(pa.y + sda.y));
      ea.z = __expf(lrelu(pa.z + sda.z)); ea.w = __expf(lrelu(pa.w + sda.w));
      eb.x = __expf(lrelu(pb.x + sdb.x)); eb.y = __expf(lrelu(pb.y + sdb.y));
      eb.z = __expf(lrelu(pb.z + sdb.z)); eb.w = __expf(lrelu(pb.w + sdb.w));
      za_x += ea.x; za_y += ea.y; za_z += ea.z; za_w += ea.w;
      zb_x += eb.x; zb_y += eb.y; zb_z += eb.z; zb_w += eb.w;
      *(float4*)&sexp[w][lane][0] = ea;
      *(float4*)&sexp[w][lane][4] = eb;
    }
    wave_fence();
    int g = 0;
    for (; g + 8 <= cnt; g += 8) {
      unsigned off[8];
      *(int4*)&off[0] = *(const int4*)&sidx[w][g];
      *(int4*)&off[4] = *(const int4*)&sidx[w][g + 4];
      unsigned uv[8];
#pragma unroll
      for (int j = 0; j < 8; ++j)
        uv[j] = *(const unsigned*)(hbc + (off[j] | lane4));   // 8 gathers in flight
#pragma unroll
      for (int j = 0; j < 8; ++j) {
        float a = sexp[w][g + j][hme];
        float2 vf = unpack_bf2(uv[j]);
        v2f v = {vf.x, vf.y};
        acc += a * v;
      }
    }
    for (; g < cnt; ++g) {
      unsigned off = (unsigned)sidx[w][g];
      unsigned uvr = *(const unsigned*)(hbc + (off | lane4));
      float a = sexp[w][g][hme];
      float2 vf = unpack_bf2(uvr);
      v2f v = {vf.x, vf.y};
      acc += a * v;
    }
    wave_fence();
  }
#pragma unroll
  for (int off = 32; off; off >>= 1) {
    za_x += __shfl_xor(za_x, off); za_y += __shfl_xor(za_y, off);
    za_z += __shfl_xor(za_z, off); za_w += __shfl_xor(za_w, off);
    zb_x += __shfl_xor(zb_x, off); zb_y += __shfl_xor(zb_y, off);
    zb_z += __shfl_xor(zb_z, off); zb_w += __shfl_xor(zb_w, off);
  }
  float zh[8] = {za_x, za_y, za_z, za_w, zb_x, zb_y, zb_z, zb_w};
  float z = zh[hme];
  float iz = z > 0.f ? 1.f / z : 0.f;
  out[(size_t)n * 64 + lane] = pack_bf2(acc.x * iz, acc.y * iz);
}

// ---------------- hetero-mean + bias + ELU (layer 1), packed in/out ----------------
__global__ void combine1_k(const unsigned* __restrict__ oa, const unsigned* __restrict__ ob,
                           const float* __restrict__ b1, unsigned* __restrict__ hmidb) {
  int idx = blockIdx.x * 256 + threadIdx.x;
  if (idx >= NN * 64) return;
  int j2 = idx & 63, j = j2 * 2;
  float2 va = unpack_bf2(oa[idx]);
  float2 vb = unpack_bf2(ob[idx]);
  float vx = 0.5f * ((va.x + b1[j]) + (vb.x + b1[128 + j]));
  float vy = 0.5f * ((va.y + b1[j + 1]) + (vb.y + b1[128 + j + 1]));
  vx = vx > 0.f ? vx : (__expf(vx) - 1.f);
  vy = vy > 0.f ? vy : (__expf(vy) - 1.f);
  hmidb[idx] = pack_bf2(vx, vy);
}

// ---------------- layer-2 folds ----------------
__global__ void fold2_k(const float* __restrict__ W2, const float* __restrict__ a2s,
                        const float* __restrict__ a2d, float* __restrict__ wsf,
                        float* __restrict__ wdf) {
  int idx = blockIdx.x * 256 + threadIdx.x;
  if (idx >= 2048) return;
  int t = idx >> 10, r = idx & 1023, hh = r >> 7, k = r & 127;
  const float* wrow = W2 + (size_t)t * 65536 + (size_t)k * 512 + hh * 64;
  const float* as = a2s + t * 512 + hh * 64;
  const float* ad = a2d + t * 512 + hh * 64;
  float s1 = 0.f, s2 = 0.f;
  for (int c = 0; c < 64; ++c) { s1 += wrow[c] * as[c]; s2 += wrow[c] * ad[c]; }
  wsf[idx] = s1; wdf[idx] = s2;
}

// fold W2 into transposed, bf16-packed MFMA B operand: BTp[t][col 64][k 1024 (512 words)]
__global__ void foldBT_k(const float* __restrict__ W2, unsigned* __restrict__ BTp) {
  int idx = blockIdx.x * 256 + threadIdx.x;
  if (idx >= 65536) return;
  int t = idx >> 15, r = idx & 32767, c = r >> 9, kw = r & 511;
  int K0 = kw * 2, K1 = K0 + 1;
  int hh0 = K0 >> 7, kk0 = K0 & 127;
  int hh1 = K1 >> 7, kk1 = K1 & 127;
  float v0 = 0.125f * W2[(size_t)t * 65536 + (size_t)kk0 * 512 + hh0 * 64 + c];
  float v1 = 0.125f * W2[(size_t)t * 65536 + (size_t)kk1 * 512 + hh1 * 64 + c];
  BTp[idx] = pack_bf2(v0, v1);
}

// ---------------- layer-2 scores from packed hmidb ----------------
__global__ void score2_k(const unsigned* __restrict__ hmidb, const float* __restrict__ wsf,
                         const float* __restrict__ wdf, float* __restrict__ ss,
                         float* __restrict__ sdo) {
  int idx = blockIdx.x * 256 + threadIdx.x;
  if (idx >= NN * 8) return;
  int n = idx >> 3, hh = idx & 7;
  const unsigned* hm = hmidb + (size_t)n * 64;
  const float* w0s = wsf + (size_t)hh * 128;
  const float* w0d = wdf + (size_t)hh * 128;
  const float* w1s = wsf + (size_t)(8 + hh) * 128;
  const float* w1d = wdf + (size_t)(8 + hh) * 128;
  float s0s = 0.f, s0d = 0.f, s1s = 0.f, s1d = 0.f;
#pragma unroll 4
  for (int q = 0; q < 64; ++q) {
    float2 f = unpack_bf2(hm[q]);
    int c = 2 * q;
    s0s += f.x * w0s[c] + f.y * w0s[c + 1];
    s0d += f.x * w0d[c] + f.y * w0d[c + 1];
    s1s += f.x * w1s[c] + f.y * w1s[c + 1];
    s1d += f.x * w1d[c] + f.y * w1d[c + 1];
  }
  ss[idx] = s0s; sdo[idx] = s0d;
  ss[NN * 8 + idx] = s1s; sdo[NN * 8 + idx] = s1d;
}

// ---------------- layer-2 aggregation: wave per node, both types, 8-deep pipelined gather ----------------
__global__ __launch_bounds__(256) void aggw2_k(const int* __restrict__ rowptr,
                                               const int* __restrict__ csr,
                                               const float* __restrict__ ssrc,
                                               const float* __restrict__ sdst,
                                               const unsigned* __restrict__ hmidb,
                                               unsigned* __restrict__ aggp) {
  int t = blockIdx.y;
  rowptr += t * (NN + 1); csr += (size_t)t * EE;
  ssrc += (size_t)t * NN * 8; sdst += (size_t)t * NN * 8;
  aggp += (size_t)t * NN * 512;
  int tid = threadIdx.x, w = tid >> 6, lane = tid & 63;
  int n = blockIdx.x * 4 + w;
  int row = rowptr[n], end = rowptr[n + 1];
  __shared__ __align__(16) int sidx[4][64];
  __shared__ __align__(16) float sexp[4][64][8];
  float4 sda = *(const float4*)&sdst[(size_t)n * 8];
  float4 sdb = *(const float4*)&sdst[(size_t)n * 8 + 4];
  float za_x = 0.f, za_y = 0.f, za_z = 0.f, za_w = 0.f;
  float zb_x = 0.f, zb_y = 0.f, zb_z = 0.f, zb_w = 0.f;
  unsigned lane4 = lane << 2;
  const char* hbc = (const char*)hmidb;
  v2f acc[8];
#pragma unroll
  for (int i = 0; i < 8; ++i) acc[i] = (v2f){0.f, 0.f};
  for (int base = row; base < end; base += 64) {
    int cnt = min(64, end - base);
    if (lane < cnt) {
      int s = csr[base + lane];
      sidx[w][lane] = s << 8;            // byte offset into hmidb
      float4 pa = *(const float4*)&ssrc[(size_t)s * 8];
      float4 pb = *(const float4*)&ssrc[(size_t)s * 8 + 4];
      float4 ea, eb;
      ea.x = __expf(lrelu(pa.x + sda.x)); ea.y = __expf(lrelu(pa.y + sda.y));
      ea.z = __expf(lrelu(pa.z + sda.z)); ea.w = __expf(lrelu(pa.w + sda.w));
      eb.x = __expf(lrelu(pb.x + sdb.x)); eb.y = __expf(lrelu(pb.y + sdb.y));
      eb.z = __expf(lrelu(pb.z + sdb.z)); eb.w = __expf(lrelu(pb.w + sdb.w));
      za_x += ea.x; za_y += ea.y; za_z += ea.z; za_w += ea.w;
      zb_x += eb.x; zb_y += eb.y; zb_z += eb.z; zb_w += eb.w;
      *(float4*)&sexp[w][lane][0] = ea;
      *(float4*)&sexp[w][lane][4] = eb;
    }
    wave_fence();
    int g = 0;
    for (; g + 8 <= cnt; g += 8) {
      unsigned off[8];
      *(int4*)&off[0] = *(const int4*)&sidx[w][g];
      *(int4*)&off[4] = *(const int4*)&sidx[w][g + 4];
      unsigned uv[8];
#pragma unroll
      for (int j = 0; j < 8; ++j)
        uv[j] = *(const unsigned*)(hbc + (off[j] | lane4));   // 8 gathers in flight
#pragma unroll
      for (int j = 0; j < 8; ++j) {
        float4 ea = *(const float4*)&sexp[w][g + j][0];
        float4 eb = *(const float4*)&sexp[w][g + j][4];
        float2 vf = unpack_bf2(uv[j]);
        v2f v = {vf.x, vf.y};
        acc[0] += ea.x * v;
        acc[1] += ea.y * v;
        acc[2] += ea.z * v;
        acc[3] += ea.w * v;
        acc[4] += eb.x * v;
        acc[5] += eb.y * v;
        acc[6] += eb.z * v;
        acc[7] += eb.w * v;
      }
    }
    for (; g < cnt; ++g) {
      unsigned off = (unsigned)sidx[w][g];
      unsigned uvr = *(const unsigned*)(hbc + (off | lane4));
      float4 ea = *(const float4*)&sexp[w][g][0];
      float4 eb = *(const float4*)&sexp[w][g][4];
      float2 vf = unpack_bf2(uvr);
      v2f v = {vf.x, vf.y};
      acc[0] += ea.x * v;
      acc[1] += ea.y * v;
      acc[2] += ea.z * v;
      acc[3] += ea.w * v;
      acc[4] += eb.x * v;
      acc[5] += eb.y * v;
      acc[6] += eb.z * v;
      acc[7] += eb.w * v;
    }
    wave_fence();
  }
#pragma unroll
  for (int off = 32; off; off >>= 1) {
    za_x += __shfl_xor(za_x, off); za_y += __shfl_xor(za_y, off);
    za_z += __shfl_xor(za_z, off); za_w += __shfl_xor(za_w, off);
    zb_x += __shfl_xor(zb_x, off); zb_y += __shfl_xor(zb_y, off);
    zb_z += __shfl_xor(zb_z, off); zb_w += __shfl_xor(zb_w, off);
  }
  float zh[8] = {za_x, za_y, za_z, za_w, zb_x, zb_y, zb_z, zb_w};
#pragma unroll
  for (int i = 0; i < 8; ++i) {
    float z = zh[i];
    float iz = z > 0.f ? 1.f / z : 0.f;
    aggp[(size_t)n * 512 + i * 64 + lane] = pack_bf2(acc[i].x * iz, acc[i].y * iz);
  }
}

// ---------------- layer-2 GEMM via MFMA: feat = ELU(0.5*(Aa*Ba + Ab*Bb + ba + bb)) ----------------
__global__ __launch_bounds__(256) void gemm2_k(const unsigned* __restrict__ Ap,
                                               const unsigned* __restrict__ BT,
                                               const float* __restrict__ b2,
                                               float* __restrict__ feat) {
  int tid = threadIdx.x, w = tid >> 6, l = tid & 63;
  int lr = l & 15, lgq = l >> 4;
  int rowbase = blockIdx.x * 64 + w * 16;
  int arow = rowbase + lr;
  if (arow > NN - 1) arow = NN - 1;   // clamp: garbage-free load, store is guarded
  f32x4 acc0 = {0.f, 0.f, 0.f, 0.f}, acc1 = acc0, acc2 = acc0, acc3 = acc0;
#pragma unroll
  for (int t = 0; t < 2; ++t) {
    const unsigned* ap = Ap + (size_t)t * NN * 512 + (size_t)arow * 512 + lgq * 4;
    const unsigned* bp = BT + t * 32768 + lr * 512 + lgq * 4;
    for (int kw = 0; kw < 512; kw += 16) {   // 32 k-elements per step
      uint4 av = *(const uint4*)(ap + kw);
      uint4 bv0 = *(const uint4*)(bp + kw);
      uint4 bv1 = *(const uint4*)(bp + 16 * 512 + kw);
      uint4 bv2 = *(const uint4*)(bp + 32 * 512 + kw);
      uint4 bv3 = *(const uint4*)(bp + 48 * 512 + kw);
      bf16x8 afq = *(const bf16x8*)&av;
      acc0 = __builtin_amdgcn_mfma_f32_16x16x32_bf16(afq, *(const bf16x8*)&bv0, acc0, 0, 0, 0);
      acc1 = __builtin_amdgcn_mfma_f32_16x16x32_bf16(afq, *(const bf16x8*)&bv1, acc1, 0, 0, 0);
      acc2 = __builtin_amdgcn_mfma_f32_16x16x32_bf16(afq, *(const bf16x8*)&bv2, acc2, 0, 0, 0);
      acc3 = __builtin_amdgcn_mfma_f32_16x16x32_bf16(afq, *(const bf16x8*)&bv3, acc3, 0, 0, 0);
    }
  }
  f32x4 accs[4] = {acc0, acc1, acc2, acc3};
#pragma unroll
  for (int ct = 0; ct < 4; ++ct) {
    int col = ct * 16 + lr;
    float bsum = b2[col] + b2[64 + col];
#pragma unroll
    for (int r = 0; r < 4; ++r) {
      int rowq = rowbase + lgq * 4 + r;
      if (rowq < NN) {
        float v = 0.5f * (accs[ct][r] + bsum);
        v = v > 0.f ? v : (__expf(v) - 1.f);
        feat[(size_t)rowq * 64 + col] = v;
      }
    }
  }
}

// ---------------- classifier ----------------
__global__ __launch_bounds__(256) void cls_k(const float* __restrict__ feat,
                                             const float* __restrict__ Wc1,
                                             const float* __restrict__ bc1,
                                             const float* __restrict__ Wc2,
                                             const float* __restrict__ bc2,
                                             float* __restrict__ out) {
  __shared__ float w1[64 * 32];
  __shared__ float w2[64];
  __shared__ float b1s[32], b2s[2];
  __shared__ float fs[8 * 64];
  __shared__ float hs[8 * 32];
  int tid = threadIdx.x;
  for (int i = tid; i < 2048; i += 256) w1[i] = Wc1[i];
  if (tid < 64) w2[tid] = Wc2[tid];
  if (tid < 32) b1s[tid] = bc1[tid];
  if (tid < 2) b2s[tid] = bc2[tid];
  int nbase = blockIdx.x * 8;
  for (int i = tid; i < 512; i += 256) fs[i] = feat[(size_t)nbase * 64 + i];
  __syncthreads();
  int local = tid >> 5, tt = tid & 31;
  const float* f = fs + local * 64;
  float acc = b1s[tt];
#pragma unroll
  for (int c = 0; c < 64; ++c) acc += f[c] * w1[c * 32 + tt];
  hs[local * 32 + tt] = fmaxf(acc, 0.f);
  __syncthreads();
  if (tid < 16) {
    int l = tid >> 1, j = tid & 1;
    float o = b2s[j];
#pragma unroll
    for (int i = 0; i < 32; ++i) o += hs[l * 32 + i] * w2[i * 2 + j];
    out[(size_t)(nbase + l) * 2 + j] = o;
  }
}

extern "C" void kernel_launch(void* const* d_in, const int* in_sizes, int n_in,
                              void* d_out, int out_size, void* d_ws, size_t ws_size,
                              hipStream_t stream) {
  const float* x   = (const float*)d_in[0];
  const int* eia   = (const int*)d_in[1];
  const int* eib   = (const int*)d_in[2];
  const float* W1  = (const float*)d_in[3];
  const float* a1s = (const float*)d_in[4];
  const float* a1d = (const float*)d_in[5];
  const float* b1  = (const float*)d_in[6];
  const float* W2  = (const float*)d_in[7];
  const float* a2s = (const float*)d_in[8];
  const float* a2d = (const float*)d_in[9];
  const float* b2  = (const float*)d_in[10];
  const float* Wc1 = (const float*)d_in[11];
  const float* bc1 = (const float*)d_in[12];
  const float* Wc2 = (const float*)d_in[13];
  const float* bc2 = (const float*)d_in[14];
  float* out = (float*)d_out;

  char* ws = (char*)d_ws;
  size_t off = 0;
  auto alloc = [&](size_t bytes) -> char* {
    char* p = ws + off;
    off += (bytes + 255) & ~(size_t)255;
    return p;
  };
  int* gcnt       = (int*)alloc((size_t)2 * NB * 4);
  int* bstart     = (int*)alloc((size_t)2 * NB * 4);
  int* bbuf       = (int*)alloc((size_t)2 * NB * BCAP * 4);
  int* rowptr     = (int*)alloc((size_t)2 * (NN + 1) * 4);
  int* csr        = (int*)alloc((size_t)2 * EE * 4);
  unsigned* Xp    = (unsigned*)alloc((size_t)NN * 128 * 4);     // bf16-packed x
  unsigned* BT1   = (unsigned*)alloc((size_t)32768 * 4);        // bf16-packed W1^T fold
  unsigned* h1b   = (unsigned*)alloc((size_t)2 * NN * 64 * 4);
  float* s1s      = (float*)alloc((size_t)2 * NN * 8 * 4);
  float* s1d      = (float*)alloc((size_t)2 * NN * 8 * 4);
  unsigned* o1p   = (unsigned*)alloc((size_t)2 * NN * 64 * 4);  // bf16-packed agg1 out
  unsigned* hmidb = (unsigned*)alloc((size_t)NN * 64 * 4);
  float* wsf      = (float*)alloc((size_t)2048 * 4);
  float* wdf      = (float*)alloc((size_t)2048 * 4);
  unsigned* BTp   = (unsigned*)alloc((size_t)65536 * 4);        // bf16-packed W2^T fold
  float* s2s      = (float*)alloc((size_t)2 * NN * 8 * 4);
  float* s2d      = (float*)alloc((size_t)2 * NN * 8 * 4);
  unsigned* aggp  = (unsigned*)alloc((size_t)2 * NN * 512 * 4); // bf16-packed agg, both types
  float* feat     = (float*)alloc((size_t)NN * 64 * 4);

  // CSR build: bucketed two-pass (grid-strided binning, packed entries)
  hipMemsetAsync(gcnt, 0, (size_t)2 * NB * 4, stream);
  bin_k<<<dim3(NBLK, 2), 256, 0, stream>>>(eia, eib, gcnt, bbuf);
  bscan_k<<<1, 512, 0, stream>>>(gcnt, bstart);
  build_k<<<dim3(NB, 2), 256, 0, stream>>>(gcnt, bstart, bbuf, rowptr, csr);

  // folds + input pack (independent; launch early)
  fold2_k<<<8, 256, 0, stream>>>(W2, a2s, a2d, wsf, wdf);
  foldBT_k<<<256, 256, 0, stream>>>(W2, BTp);
  foldBT1_k<<<128, 256, 0, stream>>>(W1, BT1);
  packx_k<<<(NN * 128 + 255) / 256, 256, 0, stream>>>(x, Xp);

  // layer 1: MFMA GEMM (both types) -> packed h1b; scores from h1b
  gemm1_k<<<(NN + 63) / 64, 256, 0, stream>>>(Xp, BT1, h1b);
  scoreb_k<<<(2 * NN * 8 + 255) / 256, 256, 0, stream>>>(h1b, a1s, a1d, s1s, s1d);
  aggw1_k<<<dim3(NN / 4, 2), 256, 0, stream>>>(rowptr, csr, s1s, s1d, h1b, o1p);
  combine1_k<<<(NN * 64 + 255) / 256, 256, 0, stream>>>(o1p, o1p + (size_t)NN * 64, b1, hmidb);

  // layer 2: scores, merged both-type aggregation (bf16 out), fused MFMA GEMM + combine + ELU
  score2_k<<<(NN * 8 + 255) / 256, 256, 0, stream>>>(hmidb, wsf, wdf, s2s, s2d);
  aggw2_k<<<dim3(NN / 4, 2), 256, 0, stream>>>(rowptr, csr, s2s, s2d, hmidb, aggp);
  gemm2_k<<<(NN + 63) / 64, 256, 0, stream>>>(aggp, BTp, b2, feat);

  // classifier
  cls_k<<<NN / 8, 256, 0, stream>>>(feat, Wc1, bc1, Wc2, bc2, out);
}